// Round 15
// baseline (113.480 us; speedup 1.0000x reference)
//
#include <hip/hip_runtime.h>
#include <cstdint>
#include <cstddef>

// MMD loss, N=8192 (b=4096), D=512.
//   R13: 256x256 TILES (traffic halved). Four delivery schemes (R6 direct,
//        R7 dbuf, R9, R12 zero-barrier) all pin k_mmd at ~43-48us with
//        constant pipe busy (VALU 16us, MFMA 6.5us) and ~266MB @ ~6TB/s
//        effective L2/L3 delivery -> the wall is BYTES PER OUTPUT, not
//        scheduling. 256^2 tiles: 528 blocks x 256KB = 135MB total.
//        512 thr / 8 waves (2x4), wave = 128x64 out, acc[8][4] (128 VGPR);
//        A panel (contiguous 128KB frag-major) one-shot into 128KB LDS
//        (reused by 4 waves), B direct from L2/L3 (reused 2x via L1),
//        ZERO barriers in K-loop. 1 blk/CU but 2 waves/SIMD (R11's fail
//        was 1/SIMD). Pred: k_mmd 25-33us, total 95-102; if >=40 ->
//        per-output epilogue floor is the wall -> pack math or roofline.
//   R12: A-in-LDS + B-direct zero-barrier (k_mmd ~44us, total 112.8).
//   R11: tiny k_bw via super-partials (KEPT). R9: hierarchical ticket.
//   R6/R7: FRAGMENT-MAJOR int8; 16-row block (rb) = contiguous 8KB;
//        256-row tile panel = contiguous 128KB. XCD swizzle bijective.
//   R4: INT8 MFMA 16x16x64 (scale 1/16, exact i32 acc), diag forced exact.
//   Epilogue: sum_k exp(-L2/(bw*2^k)) = e+e^2+e^4+e^8+e^16.

#define D_DIM 512
#define B_ROWS 4096
#define N_ROWS 8192
#define NT2 32           // 8192 / 256
#define NBLK2 528        // 32*33/2 = 8*66
#define QPITCH 528       // rowstats LDS row pitch (512 + 16 pad)

typedef __attribute__((ext_vector_type(4))) int i32x4;

__device__ inline float waveReduce(float v) {
    #pragma unroll
    for (int off = 32; off > 0; off >>= 1) v += __shfl_down(v, off, 64);
    return v;
}

__device__ inline int q8(float x) {
    int v = (int)rintf(x * 16.f);             // RNE; s = 1/16
    v = v > 127 ? 127 : v;
    v = v < -127 ? -127 : v;
    return v & 255;
}

// ---- K1: sq norms + int8 quantize (coalesced frag-major via LDS) +
//          colsum -> 8 line-spread super-partials (int atomics, exact). ----
__global__ __launch_bounds__(256) void k_rowstats(const float* __restrict__ src,
                                                  const float* __restrict__ tgt,
                                                  unsigned char* __restrict__ Tp,
                                                  float* __restrict__ sq,
                                                  int* __restrict__ sp,
                                                  unsigned int* __restrict__ tk) {
    if (blockIdx.x == 0 && threadIdx.x < 65)
        tk[threadIdx.x * 16] = 0u;           // ticket counters (replay-safe)

    __shared__ unsigned char Q[16 * QPITCH]; // 8448 B
    int tid = threadIdx.x, wave = tid >> 6, lane = tid & 63;
    int rb = blockIdx.x;                     // 0..511

    #pragma unroll
    for (int i = 0; i < 4; ++i) {
        int rl  = wave * 4 + i;
        int row = rb * 16 + rl;
        const float* base = (row < B_ROWS) ? (src + (size_t)row * D_DIM)
                                           : (tgt + (size_t)(row - B_ROWS) * D_DIM);
        float4 a = ((const float4*)base)[lane * 2];
        float4 b = ((const float4*)base)[lane * 2 + 1];
        uint2 o;  // bytes [8*lane, 8*lane+8) of the quantized row
        o.x = (unsigned)(q8(a.x) | (q8(a.y) << 8) | (q8(a.z) << 16) | (q8(a.w) << 24));
        o.y = (unsigned)(q8(b.x) | (q8(b.y) << 8) | (q8(b.z) << 16) | (q8(b.w) << 24));
        *(uint2*)(Q + rl * QPITCH + lane * 8) = o;   // 2-way bank alias: free
        float s = a.x*a.x + a.y*a.y + a.z*a.z + a.w*a.w
                + b.x*b.x + b.y*b.y + b.z*b.z + b.w*b.w;
        s = waveReduce(s);
        if (lane == 0) sq[row] = s;
    }
    __syncthreads();

    // per-rb column sums (2 cols/thread) -> atomicAdd into group rb&7.
    int s0 = 0, s1 = 0;
    #pragma unroll
    for (int r = 0; r < 16; ++r) {
        unsigned short v = *(const unsigned short*)(Q + r * QPITCH + tid * 2);
        s0 += (int)(signed char)(v & 255);
        s1 += (int)(signed char)(v >> 8);
    }
    int gbase = (rb & 7) * 512 + tid * 2;
    atomicAdd(&sp[gbase],     s0);
    atomicAdd(&sp[gbase + 1], s1);

    // frag-major writeout: thread t -> chunk c = t>>3, rows idx*2, idx*2+1.
    int c = tid >> 3, idx = tid & 7;
    uint4 lo = *(const uint4*)(Q + (idx * 2)     * QPITCH + c * 16);
    uint4 hi = *(const uint4*)(Q + (idx * 2 + 1) * QPITCH + c * 16);
    unsigned char* gout = Tp + ((size_t)rb << 13) + c * 256 + idx * 32;
    *(uint4*)(gout)      = lo;
    *(uint4*)(gout + 16) = hi;
}

// ---- K2: finalize bandwidth -> c16 = -log2(e)/(16*bw) (1 block, 16KB in) ----
__global__ __launch_bounds__(512) void k_bw(const int* __restrict__ sp,
                                            const float* __restrict__ sq,
                                            float* __restrict__ c16out) {
    int t = threadIdx.x;
    int csum = 0;
    #pragma unroll
    for (int g = 0; g < 8; ++g) csum += sp[g * 512 + t];   // coalesced, 16KB
    float cs = (float)csum * 0.0625f;          // * s (1/16)
    float p = cs * cs;
    float ssq = 0.f;
    #pragma unroll
    for (int i = 0; i < 16; ++i) ssq += sq[t + i * 512];
    __shared__ float r8[8], q8s[8];
    float wp = waveReduce(p);
    float wq = waveReduce(ssq);
    if ((t & 63) == 0) { r8[t >> 6] = wp; q8s[t >> 6] = wq; }
    __syncthreads();
    if (t == 0) {
        double P = 0.0, Q = 0.0;
        #pragma unroll
        for (int i = 0; i < 8; ++i) { P += r8[i]; Q += q8s[i]; }
        double n = (double)N_ROWS;
        double sumL2 = 2.0 * n * Q - 2.0 * P;
        double bw = sumL2 / (n * n - n) / 4.0;   // / KERNEL_MUL^(NUM/2)
        c16out[0] = (float)(-1.4426950408889634 / (16.0 * bw));
    }
}

// ---- K3: 256x256-tile A-in-LDS + B-direct Gram, zero-barrier K-loop,
//          fused MMD epilogue + hierarchical ticket ----
__global__ __launch_bounds__(512) void k_mmd(const unsigned char* __restrict__ Tp,
                                             const float* __restrict__ sq,
                                             const float* __restrict__ c16in,
                                             float* __restrict__ blockpart,
                                             float* __restrict__ out,
                                             unsigned int* __restrict__ tk) {
    int hwbid = (int)blockIdx.x;
    int bid = (hwbid & 7) * 66 + (hwbid >> 3);    // 528 = 8*66: bijective

    int rem = bid;
    int ti = 0, rowlen = NT2;
    while (rem >= rowlen) { rem -= rowlen; rowlen--; ti++; }
    int tj = ti + rem;

    int tid  = threadIdx.x;
    int wave = tid >> 6;
    int lane = tid & 63;
    int wr   = wave >> 2;                    // 0..1
    int wc   = wave & 3;                     // 0..3
    int waveM = wr * 128;
    int waveN = wc * 64;
    int l15   = lane & 15;
    int quad  = lane >> 4;

    float c16 = c16in[0];                    // -log2e/(16 bw)
    float cgq = -2.f * c16 * (1.f / 256.f);  // fold s^2 = 1/256

    // One-shot stage of the A panel (contiguous 128KB, frag-major).
    __shared__ unsigned char ldsA[131072];
    const unsigned char* gA = Tp + ((size_t)ti << 17);
    const unsigned char* gB = Tp + ((size_t)tj << 17);
    #pragma unroll
    for (int i = 0; i < 16; ++i) {
        int o = (i * 512 + tid) * 16;        // lanes linear: valid lds dest
        __builtin_amdgcn_global_load_lds(
            (const __attribute__((address_space(1))) void*)(gA + o),
            (__attribute__((address_space(3))) void*)(ldsA + o), 16, 0, 0);
    }
    __syncthreads();                         // the ONLY barrier before epilogue

    i32x4 acc[8][4];
    #pragma unroll
    for (int mi = 0; mi < 8; ++mi)
        #pragma unroll
        for (int ni = 0; ni < 4; ++ni)
            acc[mi][ni] = (i32x4){0, 0, 0, 0};

    int arow = wr * 8;                       // rb_local base of A rows (8 rb)
    int brow = wc * 4;                       // rb_local base of B cols (4 rb)
    // 8 K-steps, fully unrolled, ZERO barriers. B loads wave-private ->
    // compiler pipelines kk+1 loads under kk MFMAs. A reused by 4 waves
    // via LDS; B lines reused by wave pairs via L1.
    #pragma unroll
    for (int kk = 0; kk < 8; ++kk) {
        int coff = (kk * 4 + quad) * 256 + l15 * 16;
        i32x4 af[8], bf[4];
        #pragma unroll
        for (int ni = 0; ni < 4; ++ni)
            bf[ni] = *(const i32x4*)(gB + (size_t)((brow + ni) * 8192 + coff));
        #pragma unroll
        for (int mi = 0; mi < 8; ++mi)
            af[mi] = *(const i32x4*)(ldsA + (arow + mi) * 8192 + coff);
        #pragma unroll
        for (int mi = 0; mi < 8; ++mi)
            #pragma unroll
            for (int ni = 0; ni < 4; ++ni)
                acc[mi][ni] = __builtin_amdgcn_mfma_i32_16x16x64_i8(
                    af[mi], bf[ni], acc[mi][ni], 0, 0, 0);
    }

    const float* sqA = sq + ti * 256;
    const float* sqB = sq + tj * 256;
    float tcol16[4];
    #pragma unroll
    for (int ni = 0; ni < 4; ++ni)
        tcol16[ni] = sqB[waveN + ni * 16 + l15] * c16;

    float psum = 0.f;
    if (ti != tj) {
        // off-diagonal: no per-element diagonal check (496/528 blocks)
        #pragma unroll
        for (int mi = 0; mi < 8; ++mi) {
            float trow4[4];
            #pragma unroll
            for (int r = 0; r < 4; ++r)
                trow4[r] = sqA[waveM + mi * 16 + quad * 4 + r] * c16;
            #pragma unroll
            for (int ni = 0; ni < 4; ++ni) {
                #pragma unroll
                for (int r = 0; r < 4; ++r) {
                    float g   = (float)acc[mi][ni][r];   // exact: |G| < 2^24
                    float t16 = __builtin_fmaf(g, cgq, trow4[r]) + tcol16[ni];
                    float e1  = __builtin_amdgcn_exp2f(t16);
                    float e2  = e1 * e1;
                    float e4  = e2 * e2;
                    float e8  = e4 * e4;
                    float e16 = e8 * e8;
                    psum += ((e1 + e2) + (e4 + e8)) + e16;
                }
            }
        }
    } else {
        #pragma unroll
        for (int mi = 0; mi < 8; ++mi) {
            float trow4[4];
            #pragma unroll
            for (int r = 0; r < 4; ++r)
                trow4[r] = sqA[waveM + mi * 16 + quad * 4 + r] * c16;
            #pragma unroll
            for (int ni = 0; ni < 4; ++ni) {
                #pragma unroll
                for (int r = 0; r < 4; ++r) {
                    float g   = (float)acc[mi][ni][r];
                    float t16 = __builtin_fmaf(g, cgq, trow4[r]) + tcol16[ni];
                    float e1  = __builtin_amdgcn_exp2f(t16);
                    float e2  = e1 * e1;
                    float e4  = e2 * e2;
                    float e8  = e4 * e4;
                    float e16 = e8 * e8;
                    float ks5 = ((e1 + e2) + (e4 + e8)) + e16;
                    int rl = waveM + mi * 16 + quad * 4 + r;
                    int cl = waveN + ni * 16 + l15;
                    psum += (rl == cl) ? 5.0f : ks5;     // exact diagonal
                }
            }
        }
    }

    // Reduction scratch aliases ldsA[0..36); barrier first so no wave still
    // reads staged data.
    __syncthreads();
    float* red   = (float*)ldsA;             // bytes 0..31 (8 waves)
    int*   flagp = (int*)ldsA + 8;           // bytes 32..35
    float w = waveReduce(psum);
    if (lane == 0) red[wave] = w;
    __syncthreads();
    if (tid == 0) {
        float tot = 0.f;
        #pragma unroll
        for (int i = 0; i < 8; ++i) tot += red[i];
        float sign  = ((ti < 16) == (tj < 16)) ? 1.f : -1.f;
        float scale = (ti == tj) ? sign : 2.f * sign;
        __hip_atomic_store(&blockpart[hwbid], tot * scale,
                           __ATOMIC_RELAXED, __HIP_MEMORY_SCOPE_AGENT);
        asm volatile("s_waitcnt vmcnt(0)" ::: "memory");  // store < ticket
        unsigned g = (unsigned)hwbid & 63u;
        unsigned tgt = (g < 16u) ? 9u : 8u;               // 528 = 16*9+48*8
        unsigned prev = __hip_atomic_fetch_add(&tk[g * 16], 1u,
                            __ATOMIC_RELAXED, __HIP_MEMORY_SCOPE_AGENT);
        int last = 0;
        if (prev == tgt - 1u)
            last = (__hip_atomic_fetch_add(&tk[64 * 16], 1u,
                        __ATOMIC_RELAXED, __HIP_MEMORY_SCOPE_AGENT) == 63u);
        *flagp = last;
    }
    __syncthreads();
    if (!*flagp) return;

    // winner: every blockpart store precedes its ticket RMW; all RMWs
    // precede ours -> agent-scope loads observe all 528 values.
    float s = 0.f;
    for (int i = tid; i < NBLK2; i += 512)
        s += __hip_atomic_load(&blockpart[i], __ATOMIC_RELAXED,
                               __HIP_MEMORY_SCOPE_AGENT);
    float ws = waveReduce(s);
    __syncthreads();
    if (lane == 0) red[wave] = ws;
    __syncthreads();
    if (tid == 0) {
        float tot = 0.f;
        #pragma unroll
        for (int i = 0; i < 8; ++i) tot += red[i];
        out[0] = tot * (1.f / (4096.f * 4096.f));
    }
}

extern "C" void kernel_launch(void* const* d_in, const int* in_sizes, int n_in,
                              void* d_out, int out_size, void* d_ws, size_t ws_size,
                              hipStream_t stream) {
    const float* src = (const float*)d_in[0];
    const float* tgt = (const float*)d_in[1];

    uint8_t* ws = (uint8_t*)d_ws;
    unsigned char* Tp = (unsigned char*)ws;                     // 4,194,304 B
    size_t off = 4194304;
    float* sq      = (float*)(ws + off); off += 32768;          // 8192 f
    int*   sp      = (int*)  (ws + off); off += 16384;          // 8x512 i32
    float* bp      = (float*)(ws + off); off += 8320;
    float* c16     = (float*)(ws + off); off += 64;
    unsigned int* tk = (unsigned int*)(ws + off);               // 65*16 uints

    hipMemsetAsync(sp, 0, 16384, stream);   // zero super-partials (capturable)
    k_rowstats<<<512, 256, 0, stream>>>(src, tgt, Tp, sq, sp, tk);
    k_bw      <<<1, 512, 0, stream>>>(sp, sq, c16);
    k_mmd     <<<NBLK2, 512, 0, stream>>>(Tp, sq, c16, bp, (float*)d_out, tk);
}

// Round 16
// 113.420 us; speedup vs baseline: 1.0005x; 1.0005x over previous
//
#include <hip/hip_runtime.h>
#include <cstdint>
#include <cstddef>

// MMD loss, N=8192 (b=4096), D=512.
//   R14: FOLD k_bw INTO k_rowstats (ticket tail). R13 result: halving
//        traffic left k_mmd at 45.3us (44+-2 across TEN structural
//        variants: delivery x4, barriers 17->0, occupancy 1-4 blk/CU,
//        traffic 2x). MfmaUtil 14 + VALUBusy 31 = ~45% issue util, no
//        saturated pipe -> k_mmd's loop is NOT further addressable at
//        HIP level this session. Remaining addressable: dispatch count.
//        k_bw (2us) + its hop (~2.5us) folded into rowstats via the
//        PROVEN R9 hierarchical fence-free ticket (512 blocks -> 8
//        line-spread counters of 64 -> 1 L2 counter of 8; winner
//        computes c16). sq stores -> agent-scope (winner reads at
//        coherence point); rowstats' ticket counters zeroed by MEMSET
//        (not block 0: dispatch order undefined); k_mmd's tk stays
//        block-0-zeroed (kernel-boundary safe). c16 float-sum order
//        changes ~1ulp (int parts exact; absmax stays << tol).
//        Pred: 3 dispatches; rowstats ~8-9; k_mmd 45.3 (untouched);
//        total ~107-110. If >=113 -> revert, declare ceiling.
//   R13: 256^2 tiles, A-in-LDS(128KB) + B-direct, zero-barrier K-loop,
//        k_mmd 45.3us measured. R12: same at 128^2 (~44). R11: one-shot
//        regression (occupancy). R9: hierarchical ticket. R6: frag-major.
//   R4: INT8 MFMA 16x16x64 (scale 1/16, exact i32 acc), diag forced exact.
//   Epilogue: sum_k exp(-L2/(bw*2^k)) = e+e^2+e^4+e^8+e^16.

#define D_DIM 512
#define B_ROWS 4096
#define N_ROWS 8192
#define NT2 32           // 8192 / 256
#define NBLK2 528        // 32*33/2 = 8*66
#define QPITCH 528       // rowstats LDS row pitch (512 + 16 pad)

typedef __attribute__((ext_vector_type(4))) int i32x4;

__device__ inline float waveReduce(float v) {
    #pragma unroll
    for (int off = 32; off > 0; off >>= 1) v += __shfl_down(v, off, 64);
    return v;
}

__device__ inline int q8(float x) {
    int v = (int)rintf(x * 16.f);             // RNE; s = 1/16
    v = v > 127 ? 127 : v;
    v = v < -127 ? -127 : v;
    return v & 255;
}

// ---- K1: sq norms + int8 quantize (coalesced frag-major via LDS) +
//          colsum super-partials + (ticket tail) bandwidth -> c16. ----
__global__ __launch_bounds__(256) void k_rowstats(const float* __restrict__ src,
                                                  const float* __restrict__ tgt,
                                                  unsigned char* __restrict__ Tp,
                                                  float* __restrict__ sq,
                                                  int* __restrict__ sp,
                                                  float* __restrict__ c16out,
                                                  unsigned int* __restrict__ rtk,
                                                  unsigned int* __restrict__ tk) {
    if (blockIdx.x == 0 && threadIdx.x < 65)
        tk[threadIdx.x * 16] = 0u;           // k_mmd tickets (boundary-safe)

    __shared__ unsigned char Q[16 * QPITCH]; // 8448 B
    int tid = threadIdx.x, wave = tid >> 6, lane = tid & 63;
    int rb = blockIdx.x;                     // 0..511

    #pragma unroll
    for (int i = 0; i < 4; ++i) {
        int rl  = wave * 4 + i;
        int row = rb * 16 + rl;
        const float* base = (row < B_ROWS) ? (src + (size_t)row * D_DIM)
                                           : (tgt + (size_t)(row - B_ROWS) * D_DIM);
        float4 a = ((const float4*)base)[lane * 2];
        float4 b = ((const float4*)base)[lane * 2 + 1];
        uint2 o;  // bytes [8*lane, 8*lane+8) of the quantized row
        o.x = (unsigned)(q8(a.x) | (q8(a.y) << 8) | (q8(a.z) << 16) | (q8(a.w) << 24));
        o.y = (unsigned)(q8(b.x) | (q8(b.y) << 8) | (q8(b.z) << 16) | (q8(b.w) << 24));
        *(uint2*)(Q + rl * QPITCH + lane * 8) = o;   // 2-way bank alias: free
        float s = a.x*a.x + a.y*a.y + a.z*a.z + a.w*a.w
                + b.x*b.x + b.y*b.y + b.z*b.z + b.w*b.w;
        s = waveReduce(s);
        // agent-scope store: visible at coherence point for the ticket winner
        if (lane == 0)
            __hip_atomic_store(&sq[row], s, __ATOMIC_RELAXED,
                               __HIP_MEMORY_SCOPE_AGENT);
    }
    __syncthreads();

    // per-rb column sums (2 cols/thread) -> atomicAdd into group rb&7.
    // int adds: associative -> exact and replay-deterministic.
    int s0 = 0, s1 = 0;
    #pragma unroll
    for (int r = 0; r < 16; ++r) {
        unsigned short v = *(const unsigned short*)(Q + r * QPITCH + tid * 2);
        s0 += (int)(signed char)(v & 255);
        s1 += (int)(signed char)(v >> 8);
    }
    int gbase = (rb & 7) * 512 + tid * 2;
    atomicAdd(&sp[gbase],     s0);
    atomicAdd(&sp[gbase + 1], s1);

    // frag-major writeout: thread t -> chunk c = t>>3, rows idx*2, idx*2+1.
    int c = tid >> 3, idx = tid & 7;
    uint4 lo = *(const uint4*)(Q + (idx * 2)     * QPITCH + c * 16);
    uint4 hi = *(const uint4*)(Q + (idx * 2 + 1) * QPITCH + c * 16);
    unsigned char* gout = Tp + ((size_t)rb << 13) + c * 256 + idx * 32;
    *(uint4*)(gout)      = lo;
    *(uint4*)(gout + 16) = hi;

    // ---- ticket tail: last of 512 blocks computes c16 (replaces k_bw) ----
    // rtk zeroed by host memset (NOT block 0: dispatch order undefined).
    // __syncthreads drains every wave's stores (vmcnt 0 before s_barrier),
    // so all sp-adds / sq agent-stores precede thread 0's ticket RMW.
    __shared__ int lastflag;
    __syncthreads();
    if (tid == 0) {
        unsigned g = (unsigned)rb & 7u;      // 8 groups x 64 blocks
        unsigned prev = __hip_atomic_fetch_add(&rtk[g * 16], 1u,
                            __ATOMIC_RELAXED, __HIP_MEMORY_SCOPE_AGENT);
        int last = 0;
        if (prev == 63u)
            last = (__hip_atomic_fetch_add(&rtk[8 * 16], 1u,
                        __ATOMIC_RELAXED, __HIP_MEMORY_SCOPE_AGENT) == 7u);
        lastflag = last;
    }
    __syncthreads();
    if (!lastflag) return;

    // winner: all 512 blocks' coherent-point writes precede our reads.
    int cs0 = 0, cs1 = 0;
    #pragma unroll
    for (int g2 = 0; g2 < 8; ++g2) {
        cs0 += __hip_atomic_load(&sp[g2 * 512 + tid],
                   __ATOMIC_RELAXED, __HIP_MEMORY_SCOPE_AGENT);
        cs1 += __hip_atomic_load(&sp[g2 * 512 + 256 + tid],
                   __ATOMIC_RELAXED, __HIP_MEMORY_SCOPE_AGENT);
    }
    float c0 = (float)cs0 * 0.0625f;         // * s (1/16)
    float c1 = (float)cs1 * 0.0625f;
    float p  = c0 * c0 + c1 * c1;
    float ssq = 0.f;
    #pragma unroll
    for (int i = 0; i < 32; ++i)
        ssq += __hip_atomic_load(&sq[tid + i * 256],
                   __ATOMIC_RELAXED, __HIP_MEMORY_SCOPE_AGENT);
    float* rr = (float*)Q;                   // Q is dead: reuse as scratch
    float* qq = (float*)Q + 8;
    float wp = waveReduce(p);
    float wq = waveReduce(ssq);
    if (lane == 0) { rr[wave] = wp; qq[wave] = wq; }
    __syncthreads();
    if (tid == 0) {
        double P = 0.0, Qs = 0.0;
        #pragma unroll
        for (int i = 0; i < 4; ++i) { P += rr[i]; Qs += qq[i]; }
        double n = (double)N_ROWS;
        double sumL2 = 2.0 * n * Qs - 2.0 * P;
        double bw = sumL2 / (n * n - n) / 4.0;   // / KERNEL_MUL^(NUM/2)
        c16out[0] = (float)(-1.4426950408889634 / (16.0 * bw));
    }
}

// ---- K2: 256x256-tile A-in-LDS + B-direct Gram, zero-barrier K-loop,
//          fused MMD epilogue + hierarchical ticket (R13 verbatim) ----
__global__ __launch_bounds__(512) void k_mmd(const unsigned char* __restrict__ Tp,
                                             const float* __restrict__ sq,
                                             const float* __restrict__ c16in,
                                             float* __restrict__ blockpart,
                                             float* __restrict__ out,
                                             unsigned int* __restrict__ tk) {
    int hwbid = (int)blockIdx.x;
    int bid = (hwbid & 7) * 66 + (hwbid >> 3);    // 528 = 8*66: bijective

    int rem = bid;
    int ti = 0, rowlen = NT2;
    while (rem >= rowlen) { rem -= rowlen; rowlen--; ti++; }
    int tj = ti + rem;

    int tid  = threadIdx.x;
    int wave = tid >> 6;
    int lane = tid & 63;
    int wr   = wave >> 2;                    // 0..1
    int wc   = wave & 3;                     // 0..3
    int waveM = wr * 128;
    int waveN = wc * 64;
    int l15   = lane & 15;
    int quad  = lane >> 4;

    float c16 = c16in[0];                    // -log2e/(16 bw)
    float cgq = -2.f * c16 * (1.f / 256.f);  // fold s^2 = 1/256

    // One-shot stage of the A panel (contiguous 128KB, frag-major).
    __shared__ unsigned char ldsA[131072];
    const unsigned char* gA = Tp + ((size_t)ti << 17);
    const unsigned char* gB = Tp + ((size_t)tj << 17);
    #pragma unroll
    for (int i = 0; i < 16; ++i) {
        int o = (i * 512 + tid) * 16;        // lanes linear: valid lds dest
        __builtin_amdgcn_global_load_lds(
            (const __attribute__((address_space(1))) void*)(gA + o),
            (__attribute__((address_space(3))) void*)(ldsA + o), 16, 0, 0);
    }
    __syncthreads();                         // the ONLY barrier before epilogue

    i32x4 acc[8][4];
    #pragma unroll
    for (int mi = 0; mi < 8; ++mi)
        #pragma unroll
        for (int ni = 0; ni < 4; ++ni)
            acc[mi][ni] = (i32x4){0, 0, 0, 0};

    int arow = wr * 8;                       // rb_local base of A rows (8 rb)
    int brow = wc * 4;                       // rb_local base of B cols (4 rb)
    #pragma unroll
    for (int kk = 0; kk < 8; ++kk) {
        int coff = (kk * 4 + quad) * 256 + l15 * 16;
        i32x4 af[8], bf[4];
        #pragma unroll
        for (int ni = 0; ni < 4; ++ni)
            bf[ni] = *(const i32x4*)(gB + (size_t)((brow + ni) * 8192 + coff));
        #pragma unroll
        for (int mi = 0; mi < 8; ++mi)
            af[mi] = *(const i32x4*)(ldsA + (arow + mi) * 8192 + coff);
        #pragma unroll
        for (int mi = 0; mi < 8; ++mi)
            #pragma unroll
            for (int ni = 0; ni < 4; ++ni)
                acc[mi][ni] = __builtin_amdgcn_mfma_i32_16x16x64_i8(
                    af[mi], bf[ni], acc[mi][ni], 0, 0, 0);
    }

    const float* sqA = sq + ti * 256;
    const float* sqB = sq + tj * 256;
    float tcol16[4];
    #pragma unroll
    for (int ni = 0; ni < 4; ++ni)
        tcol16[ni] = sqB[waveN + ni * 16 + l15] * c16;

    float psum = 0.f;
    if (ti != tj) {
        #pragma unroll
        for (int mi = 0; mi < 8; ++mi) {
            float trow4[4];
            #pragma unroll
            for (int r = 0; r < 4; ++r)
                trow4[r] = sqA[waveM + mi * 16 + quad * 4 + r] * c16;
            #pragma unroll
            for (int ni = 0; ni < 4; ++ni) {
                #pragma unroll
                for (int r = 0; r < 4; ++r) {
                    float g   = (float)acc[mi][ni][r];   // exact: |G| < 2^24
                    float t16 = __builtin_fmaf(g, cgq, trow4[r]) + tcol16[ni];
                    float e1  = __builtin_amdgcn_exp2f(t16);
                    float e2  = e1 * e1;
                    float e4  = e2 * e2;
                    float e8  = e4 * e4;
                    float e16 = e8 * e8;
                    psum += ((e1 + e2) + (e4 + e8)) + e16;
                }
            }
        }
    } else {
        #pragma unroll
        for (int mi = 0; mi < 8; ++mi) {
            float trow4[4];
            #pragma unroll
            for (int r = 0; r < 4; ++r)
                trow4[r] = sqA[waveM + mi * 16 + quad * 4 + r] * c16;
            #pragma unroll
            for (int ni = 0; ni < 4; ++ni) {
                #pragma unroll
                for (int r = 0; r < 4; ++r) {
                    float g   = (float)acc[mi][ni][r];
                    float t16 = __builtin_fmaf(g, cgq, trow4[r]) + tcol16[ni];
                    float e1  = __builtin_amdgcn_exp2f(t16);
                    float e2  = e1 * e1;
                    float e4  = e2 * e2;
                    float e8  = e4 * e4;
                    float e16 = e8 * e8;
                    float ks5 = ((e1 + e2) + (e4 + e8)) + e16;
                    int rl = waveM + mi * 16 + quad * 4 + r;
                    int cl = waveN + ni * 16 + l15;
                    psum += (rl == cl) ? 5.0f : ks5;     // exact diagonal
                }
            }
        }
    }

    __syncthreads();
    float* red   = (float*)ldsA;             // bytes 0..31 (8 waves)
    int*   flagp = (int*)ldsA + 8;           // bytes 32..35
    float w = waveReduce(psum);
    if (lane == 0) red[wave] = w;
    __syncthreads();
    if (tid == 0) {
        float tot = 0.f;
        #pragma unroll
        for (int i = 0; i < 8; ++i) tot += red[i];
        float sign  = ((ti < 16) == (tj < 16)) ? 1.f : -1.f;
        float scale = (ti == tj) ? sign : 2.f * sign;
        __hip_atomic_store(&blockpart[hwbid], tot * scale,
                           __ATOMIC_RELAXED, __HIP_MEMORY_SCOPE_AGENT);
        asm volatile("s_waitcnt vmcnt(0)" ::: "memory");  // store < ticket
        unsigned g = (unsigned)hwbid & 63u;
        unsigned tgt = (g < 16u) ? 9u : 8u;               // 528 = 16*9+48*8
        unsigned prev = __hip_atomic_fetch_add(&tk[g * 16], 1u,
                            __ATOMIC_RELAXED, __HIP_MEMORY_SCOPE_AGENT);
        int last = 0;
        if (prev == tgt - 1u)
            last = (__hip_atomic_fetch_add(&tk[64 * 16], 1u,
                        __ATOMIC_RELAXED, __HIP_MEMORY_SCOPE_AGENT) == 63u);
        *flagp = last;
    }
    __syncthreads();
    if (!*flagp) return;

    float s = 0.f;
    for (int i = tid; i < NBLK2; i += 512)
        s += __hip_atomic_load(&blockpart[i], __ATOMIC_RELAXED,
                               __HIP_MEMORY_SCOPE_AGENT);
    float ws = waveReduce(s);
    __syncthreads();
    if (lane == 0) red[wave] = ws;
    __syncthreads();
    if (tid == 0) {
        float tot = 0.f;
        #pragma unroll
        for (int i = 0; i < 8; ++i) tot += red[i];
        out[0] = tot * (1.f / (4096.f * 4096.f));
    }
}

extern "C" void kernel_launch(void* const* d_in, const int* in_sizes, int n_in,
                              void* d_out, int out_size, void* d_ws, size_t ws_size,
                              hipStream_t stream) {
    const float* src = (const float*)d_in[0];
    const float* tgt = (const float*)d_in[1];

    uint8_t* ws = (uint8_t*)d_ws;
    unsigned char* Tp = (unsigned char*)ws;                     // 4,194,304 B
    size_t off = 4194304;
    float* sq      = (float*)(ws + off); off += 32768;          // 8192 f
    int*   sp      = (int*)  (ws + off); off += 16384;          // 8x512 i32
    unsigned int* rtk = (unsigned int*)(ws + off); off += 1024; // 9*16 uints
    float* bp      = (float*)(ws + off); off += 4224;           // 528 f
    float* c16     = (float*)(ws + off); off += 64;
    unsigned int* tk = (unsigned int*)(ws + off);               // 65*16 uints

    // zero sp + rtk in one memset (rtk MUST be pre-zeroed: rowstats' own
    // ticket uses it and dispatch order is undefined)
    hipMemsetAsync(sp, 0, 16384 + 1024, stream);
    k_rowstats<<<512, 256, 0, stream>>>(src, tgt, Tp, sq, sp, c16, rtk, tk);
    k_mmd     <<<NBLK2, 512, 0, stream>>>(Tp, sq, c16, bp, (float*)d_out, tk);
}

// Round 17
// 109.424 us; speedup vs baseline: 1.0371x; 1.0365x over previous
//
#include <hip/hip_runtime.h>
#include <cstdint>
#include <cstddef>

// MMD loss, N=8192 (b=4096), D=512.
//   FINAL (R15): revert to the session-best measured configuration — the
//   R7 five-kernel pipeline, benched at 108.98us (Round 3; prior session
//   110.9). All later structural variants (3-kernel folds, one-shot LDS,
//   zero-barrier K-loops, 256^2 tiles) measured 112.8-149us. Session
//   findings: k_mmd = 44+-2us invariant across TEN variants (delivery x4,
//   barriers 17->0, occupancy 1-4 blk/CU, traffic 2x, tile 128->256) with
//   NO saturated pipe (MfmaUtil 10-14, VALU 21-31, L3 3-5.5TB/s, HBM 3%,
//   conflicts 0) -> HIP-level latency/issue wall, not a roofline. Total =
//   46us harness ws-fill (unaddressable) + ~45 k_mmd wall + ~18 rest/gaps.
//   R7: LDS-STAGED k_mmd (2-phase double-buffer, global_load_lds width=16)
//       + XCD-aware block swizzle (2080 = 8*260, bijective).
//   R6: FRAGMENT-MAJOR int8 layout: chunk (rb,c) [16 rows x 16B] contiguous
//       256B; a wave's fragment load = one coalesced 1KB transaction.
//   R4: INT8 MFMA 16x16x64 (scale 1/16, exact int32 acc), diag forced exact.
//   Epilogue: sum_k exp(-L2/(bw*2^k)) = e+e^2+e^4+e^8+e^16, e=exp2(-L2*log2e/(16bw))
//   R2: no single-address atomics (were 107us of serialization).

#define D_DIM 512
#define B_ROWS 4096
#define N_ROWS 8192
#define NTILES 64        // 8192 / 128
#define NBLK_MMD 2080    // 64*65/2
#define LDS_HALF 8192    // A (or B) panel slice per K-step: 8 rb x 1KB
#define LDS_BUF 16384    // A + B per K-step

typedef __attribute__((ext_vector_type(4))) int i32x4;

__device__ inline float waveReduce(float v) {
    #pragma unroll
    for (int off = 32; off > 0; off >>= 1) v += __shfl_down(v, off, 64);
    return v;
}

__device__ inline int q8(float x) {
    int v = (int)rintf(x * 16.f);             // RNE; s = 1/16
    v = v > 127 ? 127 : v;
    v = v < -127 ? -127 : v;
    return v & 255;
}

// Fragment-major address: row r, 16B-chunk c (0..31):
//   rb = r>>4, w = r&15;  byte addr = ((rb*32 + c) << 8) + w*16

// ---- K1: per-row sq norms (fp32, exact) + fp32->int8 quantize (frag-major) ----
__global__ __launch_bounds__(256) void k_rowstats(const float* __restrict__ src,
                                                  const float* __restrict__ tgt,
                                                  unsigned char* __restrict__ Tp,
                                                  float* __restrict__ sq) {
    int wave = threadIdx.x >> 6;
    int lane = threadIdx.x & 63;
    int row  = blockIdx.x * 4 + wave;
    const float* base = (row < B_ROWS) ? (src + (size_t)row * D_DIM)
                                       : (tgt + (size_t)(row - B_ROWS) * D_DIM);
    float4 a = ((const float4*)base)[lane * 2];
    float4 b = ((const float4*)base)[lane * 2 + 1];
    uint2 o;   // bytes [8*lane, 8*lane+8) of the quantized row
    o.x = (unsigned)(q8(a.x) | (q8(a.y) << 8) | (q8(a.z) << 16) | (q8(a.w) << 24));
    o.y = (unsigned)(q8(b.x) | (q8(b.y) << 8) | (q8(b.z) << 16) | (q8(b.w) << 24));
    int rb = row >> 4, w = row & 15;
    int c  = lane >> 1, h = lane & 1;
    *(uint2*)(Tp + (((size_t)(rb * 32 + c)) << 8) + w * 16 + h * 8) = o;
    float s = a.x*a.x + a.y*a.y + a.z*a.z + a.w*a.w
            + b.x*b.x + b.y*b.y + b.z*b.z + b.w*b.w;
    s = waveReduce(s);
    if (lane == 0) sq[row] = s;
}

// ---- K2: exact int8 column-sum partials from frag-major layout ----
__global__ __launch_bounds__(256) void k_colsum(const unsigned int* __restrict__ Tu,
                                                int* __restrict__ partial) {
    int t   = threadIdx.x;
    int u   = t & 127;
    int c   = u >> 2, q = u & 3;
    int sub = t >> 7;              // w in [sub*8, sub*8+8)
    int a0 = 0, a1 = 0, a2 = 0, a3 = 0;
    #pragma unroll 2
    for (int j = 0; j < 8; ++j) {
        int rb = blockIdx.x * 8 + j;
        #pragma unroll
        for (int wv = 0; wv < 8; ++wv) {
            int w = sub * 8 + wv;
            unsigned int v = Tu[(size_t)(rb * 32 + c) * 64 + w * 4 + q];
            a0 += (int)(signed char)(v);
            a1 += (int)(signed char)(v >> 8);
            a2 += (int)(signed char)(v >> 16);
            a3 += (int)(signed char)(v >> 24);
        }
    }
    int basep = (blockIdx.x * 2 + sub) * 512 + u * 4;
    partial[basep + 0] = a0;
    partial[basep + 1] = a1;
    partial[basep + 2] = a2;
    partial[basep + 3] = a3;
}

// ---- K3: finalize bandwidth -> c16 = -log2(e)/(16*bw) ----
__global__ __launch_bounds__(512) void k_bw(const int* __restrict__ partial,
                                            const float* __restrict__ sq,
                                            float* __restrict__ c16out) {
    int t = threadIdx.x;
    int csum = 0;
    #pragma unroll 8
    for (int i = 0; i < 128; ++i) csum += partial[i * 512 + t];
    float cs = (float)csum * 0.0625f;          // * s (1/16)
    float p = cs * cs;
    float ssq = 0.f;
    #pragma unroll
    for (int i = 0; i < 16; ++i) ssq += sq[t + i * 512];
    __shared__ float r8[8], q8s[8];
    float wp = waveReduce(p);
    float wq = waveReduce(ssq);
    if ((t & 63) == 0) { r8[t >> 6] = wp; q8s[t >> 6] = wq; }
    __syncthreads();
    if (t == 0) {
        double P = 0.0, Q = 0.0;
        #pragma unroll
        for (int i = 0; i < 8; ++i) { P += r8[i]; Q += q8s[i]; }
        double n = (double)N_ROWS;
        double sumL2 = 2.0 * n * Q - 2.0 * P;
        double bw = sumL2 / (n * n - n) / 4.0;   // / KERNEL_MUL^(NUM/2)
        c16out[0] = (float)(-1.4426950408889634 / (16.0 * bw));
    }
}

// ---- K4: LDS-staged double-buffered int8 Gram + fused MMD epilogue ----
__global__ __launch_bounds__(256) void k_mmd(const unsigned char* __restrict__ Tp,
                                             const float* __restrict__ sq,
                                             const float* __restrict__ c16in,
                                             float* __restrict__ blockpart) {
    // XCD swizzle: 2080 = 8 * 260 exactly -> bijective chunked remap.
    int bid = (int)blockIdx.x;
    bid = (bid & 7) * 260 + (bid >> 3);

    int rem = bid;
    int ti = 0, rowlen = NTILES;
    while (rem >= rowlen) { rem -= rowlen; rowlen--; ti++; }
    int tj = ti + rem;

    int tid  = threadIdx.x;
    int wave = tid >> 6;
    int lane = tid & 63;
    int waveM = (wave >> 1) * 64;
    int waveN = (wave & 1) * 64;
    int l15   = lane & 15;
    int quad  = lane >> 4;

    float c16 = c16in[0];                    // -log2e/(16 bw)
    float cgq = -2.f * c16 * (1.f / 256.f);  // fold s^2 = 1/256

    int rbA0 = ti * 8;                       // panel bases (rb units)
    int rbB0 = tj * 8;

    __shared__ unsigned char lds[2 * LDS_BUF];   // 32 KB, double-buffered

    i32x4 acc[4][4];
    #pragma unroll
    for (int mi = 0; mi < 4; ++mi)
        #pragma unroll
        for (int ni = 0; ni < 4; ++ni)
            acc[mi][ni] = (i32x4){0, 0, 0, 0};

    // Stage K-step kk into buffer buf. Each wave: 4 x global_load_lds of
    // 1KB (lanes linear, 16B each). Wave w covers rb_local {2w, 2w+1} of
    // both panels. LDS layout = frag-major 1KB per rb_local, A then B.
    auto stage = [&](int buf, int kk) {
        unsigned char* lbase = lds + buf * LDS_BUF;
        #pragma unroll
        for (int s = 0; s < 2; ++s) {
            int rbl = wave * 2 + s;
            const unsigned char* gA =
                Tp + (((size_t)((rbA0 + rbl) * 32 + kk * 4)) << 8) + lane * 16;
            const unsigned char* gB =
                Tp + (((size_t)((rbB0 + rbl) * 32 + kk * 4)) << 8) + lane * 16;
            __builtin_amdgcn_global_load_lds(
                (const __attribute__((address_space(1))) void*)gA,
                (__attribute__((address_space(3))) void*)(lbase + rbl * 1024 + lane * 16),
                16, 0, 0);
            __builtin_amdgcn_global_load_lds(
                (const __attribute__((address_space(1))) void*)gB,
                (__attribute__((address_space(3))) void*)(lbase + LDS_HALF + rbl * 1024 + lane * 16),
                16, 0, 0);
        }
    };

    stage(0, 0);
    __syncthreads();                         // drains vmcnt(0) + barrier

    int aoff = ((wave >> 1) * 4) * 1024 + quad * 256 + l15 * 16;
    int boff = ((wave & 1) * 4) * 1024 + quad * 256 + l15 * 16;

    int buf = 0;
    for (int kk = 0; kk < 8; ++kk) {
        if (kk < 7) stage(buf ^ 1, kk + 1);  // prefetch next K-step

        const unsigned char* bufA = lds + buf * LDS_BUF;
        const unsigned char* bufB = bufA + LDS_HALF;
        i32x4 af[4], bf[4];
        #pragma unroll
        for (int mi = 0; mi < 4; ++mi)
            af[mi] = *(const i32x4*)(bufA + aoff + mi * 1024);
        #pragma unroll
        for (int ni = 0; ni < 4; ++ni)
            bf[ni] = *(const i32x4*)(bufB + boff + ni * 1024);
        #pragma unroll
        for (int mi = 0; mi < 4; ++mi)
            #pragma unroll
            for (int ni = 0; ni < 4; ++ni)
                acc[mi][ni] = __builtin_amdgcn_mfma_i32_16x16x64_i8(
                    af[mi], bf[ni], acc[mi][ni], 0, 0, 0);

        __syncthreads();                     // staged data ready; buf reusable
        buf ^= 1;
    }

    // epilogue: sq loads direct from global (tiny, L2-hot), pre-scaled
    const float* sqA = sq + ti * 128;
    const float* sqB = sq + tj * 128;
    float trow16[16];
    #pragma unroll
    for (int mi = 0; mi < 4; ++mi)
        #pragma unroll
        for (int r = 0; r < 4; ++r)
            trow16[mi * 4 + r] = sqA[waveM + mi * 16 + quad * 4 + r] * c16;
    float tcol16[4];
    #pragma unroll
    for (int ni = 0; ni < 4; ++ni)
        tcol16[ni] = sqB[waveN + ni * 16 + l15] * c16;

    bool dtile = (ti == tj);
    float psum = 0.f;
    #pragma unroll
    for (int mi = 0; mi < 4; ++mi) {
        #pragma unroll
        for (int ni = 0; ni < 4; ++ni) {
            #pragma unroll
            for (int r = 0; r < 4; ++r) {
                float g   = (float)acc[mi][ni][r];   // exact: |G| < 2^24
                float t16 = __builtin_fmaf(g, cgq, trow16[mi * 4 + r]) + tcol16[ni];
                float e1  = __builtin_amdgcn_exp2f(t16);
                float e2  = e1 * e1;
                float e4  = e2 * e2;
                float e8  = e4 * e4;
                float e16 = e8 * e8;
                float ks5 = ((e1 + e2) + (e4 + e8)) + e16;
                int rl = waveM + mi * 16 + quad * 4 + r;
                int cl = waveN + ni * 16 + l15;
                psum += (dtile && rl == cl) ? 5.0f : ks5;   // exact diagonal
            }
        }
    }

    // block reduction: alias scratch into lds (last frag reads are behind
    // the loop's final __syncthreads, so reuse is safe)
    float* red = (float*)lds;
    float w = waveReduce(psum);
    if (lane == 0) red[wave] = w;
    __syncthreads();
    if (tid == 0) {
        float tot   = red[0] + red[1] + red[2] + red[3];
        float sign  = ((ti < 32) == (tj < 32)) ? 1.f : -1.f;
        float scale = (ti == tj) ? sign : 2.f * sign;
        blockpart[bid] = tot * scale;        // no atomic (bid = logical id)
    }
}

// ---- K5: reduce block partials -> final scalar ----
__global__ __launch_bounds__(256) void k_final(const float* __restrict__ bp,
                                               float* __restrict__ out) {
    int t = threadIdx.x;
    float s = 0.f;
    for (int i = t; i < NBLK_MMD; i += 256) s += bp[i];
    __shared__ float r4[4];
    float w = waveReduce(s);
    if ((t & 63) == 0) r4[t >> 6] = w;
    __syncthreads();
    if (t == 0)
        out[0] = (r4[0] + r4[1] + r4[2] + r4[3]) * (1.f / (4096.f * 4096.f));
}

extern "C" void kernel_launch(void* const* d_in, const int* in_sizes, int n_in,
                              void* d_out, int out_size, void* d_ws, size_t ws_size,
                              hipStream_t stream) {
    const float* src = (const float*)d_in[0];
    const float* tgt = (const float*)d_in[1];

    uint8_t* ws = (uint8_t*)d_ws;
    unsigned char* Tp = (unsigned char*)ws;                    // 4,194,304 B
    size_t off = 4194304;
    float* sq      = (float*)(ws + off); off += 32768;         // 8192 f
    int*   partial = (int*)  (ws + off); off += 128 * 512 * 4; // 256 KB
    float* bp      = (float*)(ws + off); off += 8320;
    float* c16     = (float*)(ws + off);

    k_rowstats<<<2048, 256, 0, stream>>>(src, tgt, Tp, sq);
    k_colsum  <<<64, 256, 0, stream>>>((const unsigned int*)Tp, partial);
    k_bw      <<<1, 512, 0, stream>>>(partial, sq, c16);
    k_mmd     <<<NBLK_MMD, 256, 0, stream>>>(Tp, sq, c16, bp);
    k_final   <<<1, 256, 0, stream>>>(bp, (float*)d_out);
}